// Round 1
// baseline (2184.402 us; speedup 1.0000x reference)
//
#include <hip/hip_runtime.h>
#include <hip/hip_bf16.h>

#define Bn 64
#define Sn 256
#define In 128
#define Hn 128
#define NUNF 6
#define EPSC 1e-8f
#define L2E 1.4426950408889634f
#define TT 16
#define QG 4
#define JPT 32

// ---------------- workspace layout (floats) ----------------
enum {
  OFF_A2   = 0,                    // -sigma*log2e          (H*H)
  OFF_B2   = OFF_A2   + Hn*Hn,     //  sigma*mu*log2e       (H*H)
  OFF_W    = OFF_B2   + Hn*Hn,     //  softplus(w)          (H*H)
  OFF_WE   = OFF_W    + Hn*Hn,     //  softplus(w)*erev     (H*H)
  OFF_SA2  = OFF_WE   + Hn*Hn,     //  sensory equivalents  (I*H)
  OFF_SB2  = OFF_SA2  + In*Hn,
  OFF_SW   = OFF_SB2  + In*Hn,
  OFF_SWE  = OFF_SW   + In*Hn,
  OFF_PHT  = OFF_SWE  + In*Hn,     //  phase_W^T [j][h]     (H*H)
  OFF_SAT  = OFF_PHT  + Hn*Hn,     //  sa_W^T [j][h]        (H*H)
  OFF_CMT  = OFF_SAT  + Hn*Hn,     //  softplus(cm)*UNFOLDS (H)
  OFF_GL   = OFF_CMT  + Hn,        //  softplus(gleak)      (H)
  OFF_GLV  = OFF_GL   + Hn,        //  gl*vleak             (H)
  OFF_AAMP = OFF_GLV  + Hn,        //  alpha*amplitude      (H)
  OFF_NUMS = OFF_AAMP + Hn,        //  sensory num (B,S,H)
  OFF_DENS = OFF_NUMS + Bn*Sn*Hn,  //  sensory den (B,S,H)
  WS_FLOATS = OFF_DENS + Bn*Sn*Hn
};

// ---------------- fast math wrappers ----------------
__device__ __forceinline__ float fexp2(float x) {
#if __has_builtin(__builtin_amdgcn_exp2f)
  return __builtin_amdgcn_exp2f(x);
#else
  return exp2f(x);
#endif
}
__device__ __forceinline__ float frcp(float x) {
#if __has_builtin(__builtin_amdgcn_rcpf)
  return __builtin_amdgcn_rcpf(x);
#else
  return 1.0f / x;
#endif
}
__device__ __forceinline__ float fsigmoid(float x) {
  return frcp(1.0f + fexp2(-x * L2E));
}
__device__ __forceinline__ float fast_sin(float ang) {
#if __has_builtin(__builtin_amdgcn_sinf)
  // v_sin_f32 takes revolutions; reduce explicitly.
  float r = ang * 0.15915494309189535f;
  r = r - rintf(r);
  return __builtin_amdgcn_sinf(r);
#else
  return sinf(ang);
#endif
}

// ---------------- kernel 1: parameter transforms ----------------
__global__ void k_prep(const float* __restrict__ sigma, const float* __restrict__ mu,
                       const float* __restrict__ w, const float* __restrict__ erev,
                       const float* __restrict__ s_sigma, const float* __restrict__ s_mu,
                       const float* __restrict__ s_w, const float* __restrict__ s_erev,
                       const float* __restrict__ gleak, const float* __restrict__ vleak,
                       const float* __restrict__ cm, const float* __restrict__ amplitude,
                       const float* __restrict__ alpha_p,
                       const float* __restrict__ phase_W, const float* __restrict__ sa_W,
                       float* __restrict__ ws)
{
  int i = blockIdx.x * blockDim.x + threadIdx.x;
  if (i >= Hn * Hn) return;
  {
    float sg = sigma[i];
    ws[OFF_A2 + i] = -sg * L2E;
    ws[OFF_B2 + i] = sg * mu[i] * L2E;
    float Wv = log1pf(expf(w[i]));          // softplus
    ws[OFF_W  + i] = Wv;
    ws[OFF_WE + i] = Wv * erev[i];
  }
  {
    float ss = s_sigma[i];
    ws[OFF_SA2 + i] = -ss * L2E;
    ws[OFF_SB2 + i] = ss * s_mu[i] * L2E;
    float SWv = log1pf(expf(s_w[i]));
    ws[OFF_SW  + i] = SWv;
    ws[OFF_SWE + i] = SWv * s_erev[i];
  }
  {
    int j = i >> 7, h = i & (Hn - 1);
    ws[OFF_PHT + i] = phase_W[h * Hn + j];  // transpose to [j][h]
    ws[OFF_SAT + i] = sa_W[h * Hn + j];
  }
  if (i < Hn) {
    float gl = log1pf(expf(gleak[i]));
    ws[OFF_CMT  + i] = log1pf(expf(cm[i])) * (float)NUNF;  // DT == 1
    ws[OFF_GL   + i] = gl;
    ws[OFF_GLV  + i] = gl * vleak[i];
    ws[OFF_AAMP + i] = alpha_p[0] * amplitude[i];
  }
}

// ---------------- kernel 2: sensory synapse sums (fully parallel) ----------------
__global__ __launch_bounds__(128, 4) void k_sensory(
    const float* __restrict__ x, const float* __restrict__ input_w,
    const float* __restrict__ input_b, const float* __restrict__ ws,
    float* __restrict__ onum, float* __restrict__ oden)
{
  __shared__ float xs[TT * In];
  int b = blockIdx.x, tc = blockIdx.y;
  int t0 = tc * TT;
  int h = threadIdx.x;

  for (int k = h; k < TT * In; k += 128) {
    int tt = k >> 7, i = k & (In - 1);
    xs[k] = x[((size_t)b * Sn + t0 + tt) * In + i] * input_w[i] + input_b[i];
  }
  __syncthreads();

  const float* sa2 = ws + OFF_SA2;
  const float* sb2 = ws + OFF_SB2;
  const float* SW  = ws + OFF_SW;
  const float* SWE = ws + OFF_SWE;

  float num[TT], den[TT];
#pragma unroll
  for (int tt = 0; tt < TT; tt++) { num[tt] = 0.f; den[tt] = 0.f; }

  for (int i = 0; i < In; i++) {
    float A  = sa2[i * Hn + h];
    float Bc = sb2[i * Hn + h];
    float Wv = SW [i * Hn + h];
    float Ev = SWE[i * Hn + h];
#pragma unroll
    for (int tt = 0; tt < TT; tt++) {
      float e = fexp2(fmaf(A, xs[tt * In + i], Bc));
      float r = frcp(1.0f + e);
      den[tt] = fmaf(Wv, r, den[tt]);
      num[tt] = fmaf(Ev, r, num[tt]);
    }
  }
#pragma unroll
  for (int tt = 0; tt < TT; tt++) {
    size_t o = ((size_t)b * Sn + t0 + tt) * Hn + h;
    onum[o] = num[tt];
    oden[o] = den[tt];
  }
}

// ---------------- kernel 3: recurrent scan (1 block == 1 batch chain) ----------------
__global__ __launch_bounds__(512, 2) void k_recurrent(
    const float* __restrict__ ws, const float* __restrict__ h0,
    const float* __restrict__ omega, const float* __restrict__ phase_b,
    const float* __restrict__ beta_p, float* __restrict__ out)
{
  __shared__ float phT_s[Hn * Hn];       // 64 KB
  __shared__ float saT_s[Hn * Hn];       // 64 KB
  __shared__ __align__(16) float vbuf[Hn];
  __shared__ float sgbuf[Hn];
  __shared__ float pnum[QG][Hn];
  __shared__ float pden[QG][Hn];

  int b = blockIdx.x;
  int tid = threadIdx.x;
  int h = tid & (Hn - 1);
  int q = tid >> 7;            // 0..3, wave-uniform
  int j0 = q * JPT;

  // per-thread recurrent synapse params in registers (32 j x 4 = 128 VGPR)
  float a2[JPT], b2[JPT], Wr[JPT], WEr[JPT];
#pragma unroll
  for (int k = 0; k < JPT; k++) {
    int idx = (j0 + k) * Hn + h;
    a2[k]  = ws[OFF_A2 + idx];
    b2[k]  = ws[OFF_B2 + idx];
    Wr[k]  = ws[OFF_W  + idx];
    WEr[k] = ws[OFF_WE + idx];
  }
  for (int k = tid; k < Hn * Hn; k += 512) {
    phT_s[k] = ws[OFF_PHT + k];
    saT_s[k] = ws[OFF_SAT + k];
  }

  float cmt  = ws[OFF_CMT  + h];
  float gl   = ws[OFF_GL   + h];
  float glv  = ws[OFF_GLV  + h];
  float aamp = ws[OFF_AAMP + h];
  float om   = omega[h];
  float phb  = phase_b[h];
  float beta = beta_p[0];

  const float* nums = ws + OFF_NUMS + (size_t)b * Sn * Hn;
  const float* dens = ws + OFF_DENS + (size_t)b * Sn * Hn;
  float* outb = out + (size_t)b * Sn * Hn;

  if (tid < Hn) vbuf[tid] = h0[b * Hn + tid];
  __syncthreads();

  for (int t = 0; t < Sn; t++) {
    float sn = 0.f, sd = 0.f;
    if (tid < Hn) { sn = nums[t * Hn + tid]; sd = dens[t * Hn + tid]; }

    // ---- 6 semi-implicit ODE unfolds ----
    for (int u = 0; u < NUNF; u++) {
      float num = 0.f, den = 0.f;
#pragma unroll
      for (int k4 = 0; k4 < JPT; k4 += 4) {
        float4 vv = *(const float4*)(vbuf + j0 + k4);
        float vj[4] = {vv.x, vv.y, vv.z, vv.w};
#pragma unroll
        for (int m = 0; m < 4; m++) {
          int k = k4 + m;
          float e = fexp2(fmaf(a2[k], vj[m], b2[k]));
          float r = frcp(1.0f + e);
          den = fmaf(Wr[k],  r, den);
          num = fmaf(WEr[k], r, num);
        }
      }
      pnum[q][h] = num;
      pden[q][h] = den;
      __syncthreads();
      if (tid < Hn) {
        float wn = sn + pnum[0][tid] + pnum[1][tid] + pnum[2][tid] + pnum[3][tid];
        float wd = sd + pden[0][tid] + pden[1][tid] + pden[2][tid] + pden[3][tid];
        float v = vbuf[tid];
        vbuf[tid] = (cmt * v + glv + wn) / (cmt + gl + wd + EPSC);
      }
      __syncthreads();
    }

    // ---- oscillatory pulse: phi = v @ phase_W^T + phase_b ----
    {
      float acc = 0.f;
#pragma unroll
      for (int k = 0; k < JPT; k++)
        acc = fmaf(phT_s[(j0 + k) * Hn + h], vbuf[j0 + k], acc);
      pnum[q][h] = acc;
    }
    __syncthreads();
    if (tid < Hn) {
      float phi = phb + pnum[0][tid] + pnum[1][tid] + pnum[2][tid] + pnum[3][tid];
      float v = vbuf[tid];
      v += aamp * fast_sin(om * (float)t + phi);
      sgbuf[tid] = fsigmoid(v);
      vbuf[tid] = v;
    }
    __syncthreads();

    // ---- self-attend: v += beta * (sigmoid(v) @ sa_W^T) ----
    {
      float acc = 0.f;
#pragma unroll
      for (int k = 0; k < JPT; k++)
        acc = fmaf(saT_s[(j0 + k) * Hn + h], sgbuf[j0 + k], acc);
      pnum[q][h] = acc;
    }
    __syncthreads();
    if (tid < Hn) {
      float v = vbuf[tid] + beta * (pnum[0][tid] + pnum[1][tid] + pnum[2][tid] + pnum[3][tid]);
      vbuf[tid] = v;
      outb[t * Hn + tid] = v;
    }
    __syncthreads();
  }

  if (tid < Hn) out[(size_t)Bn * Sn * Hn + b * Hn + tid] = vbuf[tid];
}

// ---------------- launcher ----------------
extern "C" void kernel_launch(void* const* d_in, const int* in_sizes, int n_in,
                              void* d_out, int out_size, void* d_ws, size_t ws_size,
                              hipStream_t stream) {
  const float* x         = (const float*)d_in[0];
  const float* h0        = (const float*)d_in[1];
  const float* input_w   = (const float*)d_in[2];
  const float* input_b   = (const float*)d_in[3];
  const float* gleak     = (const float*)d_in[4];
  const float* vleak     = (const float*)d_in[5];
  const float* cm        = (const float*)d_in[6];
  const float* sigma     = (const float*)d_in[7];
  const float* mu        = (const float*)d_in[8];
  const float* w         = (const float*)d_in[9];
  const float* erev      = (const float*)d_in[10];
  const float* s_sigma   = (const float*)d_in[11];
  const float* s_mu      = (const float*)d_in[12];
  const float* s_w       = (const float*)d_in[13];
  const float* s_erev    = (const float*)d_in[14];
  const float* amplitude = (const float*)d_in[15];
  const float* omega     = (const float*)d_in[16];
  const float* phase_W   = (const float*)d_in[17];
  const float* phase_b   = (const float*)d_in[18];
  const float* alpha     = (const float*)d_in[19];
  const float* sa_W      = (const float*)d_in[20];
  const float* beta      = (const float*)d_in[21];

  float* ws  = (float*)d_ws;
  float* out = (float*)d_out;

  hipLaunchKernelGGL(k_prep, dim3(64), dim3(256), 0, stream,
                     sigma, mu, w, erev, s_sigma, s_mu, s_w, s_erev,
                     gleak, vleak, cm, amplitude, alpha, phase_W, sa_W, ws);
  hipLaunchKernelGGL(k_sensory, dim3(Bn, Sn / TT), dim3(128), 0, stream,
                     x, input_w, input_b, ws, ws + OFF_NUMS, ws + OFF_DENS);
  hipLaunchKernelGGL(k_recurrent, dim3(Bn), dim3(512), 0, stream,
                     ws, h0, omega, phase_b, beta, out);
}